// Round 11
// baseline (341.087 us; speedup 1.0000x reference)
//
#include <hip/hip_runtime.h>
#include <hip/hip_bf16.h>

typedef __hip_bfloat16 bf16;
typedef __attribute__((ext_vector_type(8))) short short8;
typedef __attribute__((ext_vector_type(4))) float f32x4;

#define FDIM 64
#define HDIM 128
#define SCHUNK 512
#define PROWS 256

__device__ __forceinline__ float b2f(bf16 v) { return __bfloat162float(v); }
__device__ __forceinline__ float bits2f(unsigned int u) {
    return __uint_as_float(u << 16);
}
__device__ __forceinline__ unsigned short f2bits(float f) {
    bf16 b = __float2bfloat16(f);
    return *reinterpret_cast<unsigned short*>(&b);
}

// ---------------- flags ----------------
__global__ __launch_bounds__(192) void k_prep_flags(const unsigned short* __restrict__ w1u,
                                                    const int* __restrict__ edge,
                                                    const int* __restrict__ batch,
                                                    int* __restrict__ flags) {
    int wave = threadIdx.x >> 6, lane = threadIdx.x & 63;
    if (wave == 0) {
        int wild = 0;
#pragma unroll
        for (int r = 0; r < 2; r++) {
            int i = 2 * lane + 128 * r;
            int e = (w1u[i] >> 7) & 0xFF;
            wild += (e == 0 || e >= 137) ? 1 : 0;
        }
        for (int s = 32; s; s >>= 1) wild += __shfl_down(wild, s);
        if (lane == 0) flags[0] = (wild > 16) ? 1 : 0;
    } else if (wave == 1) {
        int z = 0;
#pragma unroll
        for (int r = 0; r < 2; r++) {
            int i = 2 * lane + 1 + 128 * r;
            z += (edge[i] == 0) ? 1 : 0;
        }
        for (int s = 32; s; s >>= 1) z += __shfl_down(z, s);
        if (lane == 0) flags[1] = (z > 64) ? 1 : 0;
    } else {
        int z = 0;
#pragma unroll
        for (int r = 0; r < 2; r++) {
            int i = 1025 + 2 * lane + 128 * r;
            z += (batch[i] == 0) ? 1 : 0;
        }
        for (int s = 32; s; s >>= 1) z += __shfl_down(z, s);
        if (lane == 0) flags[2] = (z > 64) ? 1 : 0;
    }
}

// ---------------- weights conv ----------------
__global__ __launch_bounds__(256) void k_prep_conv(const void* __restrict__ W1,
                                                   const void* __restrict__ b1,
                                                   const void* __restrict__ W2,
                                                   const void* __restrict__ b2,
                                                   const void* __restrict__ Wfc,
                                                   const void* __restrict__ bfc,
                                                   const int* __restrict__ flags,
                                                   bf16* __restrict__ W1t, bf16* __restrict__ W2t,
                                                   bf16* __restrict__ b1c, bf16* __restrict__ b2c,
                                                   bf16* __restrict__ Wfcc, bf16* __restrict__ bfcc) {
    int f0 = flags[0];
    int gid = blockIdx.x * 256 + threadIdx.x;
    int stride = gridDim.x * 256;
#define CV(src, si) (f0 ? __float2bfloat16(((const float*)(src))[si]) : ((const bf16*)(src))[si])
    for (int i = gid; i < FDIM * HDIM; i += stride) {
        int n = i >> 6, k = i & 63;
        W1t[i] = CV(W1, k * HDIM + n);
    }
    for (int i = gid; i < HDIM * HDIM; i += stride) {
        int n = i >> 7, k = i & 127;
        W2t[i] = CV(W2, k * HDIM + n);
    }
    for (int i = gid; i < HDIM; i += stride) b1c[i] = CV(b1, i);
    for (int i = gid; i < HDIM; i += stride) b2c[i] = CV(b2, i);
    for (int i = gid; i < HDIM * 2; i += stride) Wfcc[i] = CV(Wfc, i);
    for (int i = gid; i < 2; i += stride) bfcc[i] = CV(bfc, i);
#undef CV
}

// ---------------- convert X to bf16 ----------------
__global__ __launch_bounds__(256) void k_convX(const void* __restrict__ x,
                                               bf16* __restrict__ Xb, int total4,
                                               const int* __restrict__ flags) {
    int t = blockIdx.x * 256 + threadIdx.x;
    if (t >= total4) return;
    if (flags[0]) {
        float4 v = ((const float4*)x)[t];
        uint2 p;
        p.x = ((unsigned int)f2bits(v.y) << 16) | f2bits(v.x);
        p.y = ((unsigned int)f2bits(v.w) << 16) | f2bits(v.z);
        ((uint2*)Xb)[t] = p;
    } else {
        ((uint2*)Xb)[t] = ((const uint2*)x)[t];
    }
}

__device__ __forceinline__ int edge_word(const int* e, long long logical_idx, int is64) {
    return is64 ? e[2 * logical_idx] : e[logical_idx];
}

// ---------------- CSR build (2 edges/thread) ----------------
__global__ void k_count(const int* __restrict__ edge, int* __restrict__ count,
                        int* __restrict__ rank, int E, int Eh,
                        const int* __restrict__ flags) {
    int i = blockIdx.x * blockDim.x + threadIdx.x;
    int is64 = flags[1];
    if (i < Eh) {
        int d = edge_word(edge, (long long)E + i, is64);
        rank[i] = atomicAdd(&count[d], 1);
    }
    int i2 = i + Eh;
    if (i2 < E) {
        int d2 = edge_word(edge, (long long)E + i2, is64);
        rank[i2] = atomicAdd(&count[d2], 1);
    }
}

__global__ __launch_bounds__(256) void k_scan_partial(const int* __restrict__ count,
                                                      int* __restrict__ parts, int N) {
    __shared__ int red[256];
    int base = blockIdx.x * SCHUNK;
    int t = threadIdx.x;
    int i0 = base + 2 * t, i1 = base + 2 * t + 1;
    int v = 0;
    if (i0 < N) v += count[i0];
    if (i1 < N) v += count[i1];
    red[t] = v;
    __syncthreads();
    for (int s = 128; s > 0; s >>= 1) {
        if (t < s) red[t] += red[t + s];
        __syncthreads();
    }
    if (t == 0) parts[blockIdx.x] = red[0];
}

__global__ __launch_bounds__(256) void k_scan_parts(const int* __restrict__ parts,
                                                    int* __restrict__ partsx, int NP) {
    __shared__ int a[256], b[256];
    int t = threadIdx.x;
    int own = (t < NP) ? parts[t] : 0;
    a[t] = own;
    __syncthreads();
    int* cur = a; int* nxt = b;
    for (int off = 1; off < 256; off <<= 1) {
        int v = cur[t];
        if (t >= off) v += cur[t - off];
        nxt[t] = v;
        __syncthreads();
        int* tmp = cur; cur = nxt; nxt = tmp;
    }
    if (t < NP) partsx[t] = cur[t] - own;
}

__global__ __launch_bounds__(512) void k_scan_final(const int* __restrict__ count,
                                                    const int* __restrict__ partsx,
                                                    int* __restrict__ rowptr,
                                                    float* __restrict__ dinv, int N) {
    __shared__ int a[512], b[512];
    int t = threadIdx.x;
    int idx = blockIdx.x * SCHUNK + t;
    int own = (idx < N) ? count[idx] : 0;
    a[t] = own;
    __syncthreads();
    int* cur = a; int* nxt = b;
    for (int off = 1; off < 512; off <<= 1) {
        int v = cur[t];
        if (t >= off) v += cur[t - off];
        nxt[t] = v;
        __syncthreads();
        int* tmp = cur; cur = nxt; nxt = tmp;
    }
    if (idx < N) {
        rowptr[idx] = cur[t] - own + partsx[blockIdx.x];
        dinv[idx] = rsqrtf((float)own + 1.0f);
    }
}

__global__ void k_fill(const int* __restrict__ edge, const int* __restrict__ rowptr,
                       const int* __restrict__ rank, int* __restrict__ srclist,
                       int E, int Eh, const int* __restrict__ flags) {
    int i = blockIdx.x * blockDim.x + threadIdx.x;
    int is64 = flags[1];
    if (i < Eh) {
        int s = edge_word(edge, i, is64);
        int d = edge_word(edge, (long long)E + i, is64);
        srclist[rowptr[d] + rank[i]] = s;
    }
    int i2 = i + Eh;
    if (i2 < E) {
        int s2 = edge_word(edge, i2, is64);
        int d2 = edge_word(edge, (long long)E + i2, is64);
        srclist[rowptr[d2] + rank[i2]] = s2;
    }
}

#define ACC8(v, e) do { \
    acc[0] += bits2f((v).x & 0xFFFFu) * (e); acc[1] += bits2f((v).x >> 16) * (e); \
    acc[2] += bits2f((v).y & 0xFFFFu) * (e); acc[3] += bits2f((v).y >> 16) * (e); \
    acc[4] += bits2f((v).z & 0xFFFFu) * (e); acc[5] += bits2f((v).z >> 16) * (e); \
    acc[6] += bits2f((v).w & 0xFFFFu) * (e); acc[7] += bits2f((v).w >> 16) * (e); } while (0)

// ---------------- agg64: wave per node; 8 groups x 8 lanes; 8 neighbors/step ----------------
__global__ __launch_bounds__(256) void k_agg64(const bf16* __restrict__ h,
                                               const int* __restrict__ srclist,
                                               const int* __restrict__ rowptr,
                                               const int* __restrict__ count,
                                               const float* __restrict__ dinv,
                                               bf16* __restrict__ outb, int N) {
    int wave = threadIdx.x >> 6;
    int lane = threadIdx.x & 63;
    int group = lane >> 3;
    int sub = lane & 7;
    int i = blockIdx.x * 4 + wave;
    if (i >= N) return;
    int start = rowptr[i];
    int cnt = count[i];
    float di = dinv[i];
    const uint4* hrow = (const uint4*)h;
    float acc[8] = {0.f, 0.f, 0.f, 0.f, 0.f, 0.f, 0.f, 0.f};
    for (int base = 0; base < cnt; base += 64) {
        int nb = cnt - base; if (nb > 64) nb = 64;
        int sv = 0; float dvv = 0.f;
        if (lane < nb) { sv = srclist[start + base + lane]; dvv = dinv[sv]; }
        int j = 0;
        for (; j + 16 <= nb; j += 16) {
            int sA = __shfl(sv, j + group);      float eA = __shfl(dvv, j + group);
            int sB = __shfl(sv, j + 8 + group);  float eB = __shfl(dvv, j + 8 + group);
            uint4 vA = hrow[(size_t)sA * 8 + sub];
            uint4 vB = hrow[(size_t)sB * 8 + sub];
            ACC8(vA, eA); ACC8(vB, eB);
        }
        for (; j < nb; j += 8) {
            if (j + group < nb) {
                int sA = __shfl(sv, j + group); float eA = __shfl(dvv, j + group);
                uint4 vA = hrow[(size_t)sA * 8 + sub];
                ACC8(vA, eA);
            }
        }
    }
#pragma unroll
    for (int k = 0; k < 8; k++) {
        acc[k] += __shfl_xor(acc[k], 8);
        acc[k] += __shfl_xor(acc[k], 16);
        acc[k] += __shfl_xor(acc[k], 32);
    }
    if (group == 0) {
        uint4 vs = hrow[(size_t)i * 8 + sub];
        float self = di * di;
        float o0 = di * acc[0] + bits2f(vs.x & 0xFFFFu) * self;
        float o1 = di * acc[1] + bits2f(vs.x >> 16) * self;
        float o2 = di * acc[2] + bits2f(vs.y & 0xFFFFu) * self;
        float o3 = di * acc[3] + bits2f(vs.y >> 16) * self;
        float o4 = di * acc[4] + bits2f(vs.z & 0xFFFFu) * self;
        float o5 = di * acc[5] + bits2f(vs.z >> 16) * self;
        float o6 = di * acc[6] + bits2f(vs.w & 0xFFFFu) * self;
        float o7 = di * acc[7] + bits2f(vs.w >> 16) * self;
        uint4 pv;
        pv.x = ((unsigned int)f2bits(o1) << 16) | f2bits(o0);
        pv.y = ((unsigned int)f2bits(o3) << 16) | f2bits(o2);
        pv.z = ((unsigned int)f2bits(o5) << 16) | f2bits(o4);
        pv.w = ((unsigned int)f2bits(o7) << 16) | f2bits(o6);
        ((uint4*)outb)[(size_t)i * 8 + sub] = pv;
    }
}

// ---------------- agg128: wave per node; 4 groups x 16 lanes; 4 neighbors/step ----------------
__global__ __launch_bounds__(256) void k_agg128(const bf16* __restrict__ h,
                                                const int* __restrict__ srclist,
                                                const int* __restrict__ rowptr,
                                                const int* __restrict__ count,
                                                const float* __restrict__ dinv,
                                                bf16* __restrict__ outb, int N) {
    int wave = threadIdx.x >> 6;
    int lane = threadIdx.x & 63;
    int group = lane >> 4;
    int sub = lane & 15;
    int i = blockIdx.x * 4 + wave;
    if (i >= N) return;
    int start = rowptr[i];
    int cnt = count[i];
    float di = dinv[i];
    const uint4* hrow = (const uint4*)h;
    float acc[8] = {0.f, 0.f, 0.f, 0.f, 0.f, 0.f, 0.f, 0.f};
    for (int base = 0; base < cnt; base += 64) {
        int nb = cnt - base; if (nb > 64) nb = 64;
        int sv = 0; float dvv = 0.f;
        if (lane < nb) { sv = srclist[start + base + lane]; dvv = dinv[sv]; }
        int j = 0;
        for (; j + 8 <= nb; j += 8) {
            int sA = __shfl(sv, j + group);      float eA = __shfl(dvv, j + group);
            int sB = __shfl(sv, j + 4 + group);  float eB = __shfl(dvv, j + 4 + group);
            uint4 vA = hrow[(size_t)sA * 16 + sub];
            uint4 vB = hrow[(size_t)sB * 16 + sub];
            ACC8(vA, eA); ACC8(vB, eB);
        }
        for (; j < nb; j += 4) {
            if (j + group < nb) {
                int sA = __shfl(sv, j + group); float eA = __shfl(dvv, j + group);
                uint4 vA = hrow[(size_t)sA * 16 + sub];
                ACC8(vA, eA);
            }
        }
    }
#pragma unroll
    for (int k = 0; k < 8; k++) {
        acc[k] += __shfl_xor(acc[k], 16);
        acc[k] += __shfl_xor(acc[k], 32);
    }
    if (group == 0) {
        uint4 vs = hrow[(size_t)i * 16 + sub];
        float self = di * di;
        float o0 = di * acc[0] + bits2f(vs.x & 0xFFFFu) * self;
        float o1 = di * acc[1] + bits2f(vs.x >> 16) * self;
        float o2 = di * acc[2] + bits2f(vs.y & 0xFFFFu) * self;
        float o3 = di * acc[3] + bits2f(vs.y >> 16) * self;
        float o4 = di * acc[4] + bits2f(vs.z & 0xFFFFu) * self;
        float o5 = di * acc[5] + bits2f(vs.z >> 16) * self;
        float o6 = di * acc[6] + bits2f(vs.w & 0xFFFFu) * self;
        float o7 = di * acc[7] + bits2f(vs.w >> 16) * self;
        uint4 pv;
        pv.x = ((unsigned int)f2bits(o1) << 16) | f2bits(o0);
        pv.y = ((unsigned int)f2bits(o3) << 16) | f2bits(o2);
        pv.z = ((unsigned int)f2bits(o5) << 16) | f2bits(o4);
        pv.w = ((unsigned int)f2bits(o7) << 16) | f2bits(o6);
        ((uint4*)outb)[(size_t)i * 16 + sub] = pv;
    }
}

// ---------------- MFMA GEMM A: h1 = relu(Y @ W1 + b1) ----------------
#define K1PAD 72
__global__ __launch_bounds__(256) void k_gemmA(const bf16* __restrict__ Y,
                                               const bf16* __restrict__ W1t,
                                               const bf16* __restrict__ bias,
                                               bf16* __restrict__ h1, int N) {
    __shared__ bf16 As[64 * K1PAD];
    __shared__ bf16 Wt[HDIM * K1PAD];
    __shared__ float bsf[HDIM];
    int tid = threadIdx.x;
    int base = blockIdx.x * 64;
    {
        const uint4* wsrc = (const uint4*)W1t;
        for (int i = tid; i < HDIM * 8; i += 256) {
            int n = i >> 3, c = i & 7;
            *(uint4*)&Wt[n * K1PAD + c * 8] = wsrc[n * 8 + c];
        }
    }
    {
        const uint4* xb = (const uint4*)Y;
        for (int i = tid; i < 64 * 8; i += 256) {
            int r = i >> 3, c = i & 7;
            int gr = base + r; if (gr >= N) gr = N - 1;
            *(uint4*)&As[r * K1PAD + c * 8] = xb[(size_t)gr * 8 + c];
        }
    }
    if (tid < HDIM) bsf[tid] = b2f(bias[tid]);
    __syncthreads();
    int wid = tid >> 6, lane = tid & 63;
    int l15 = lane & 15, q = lane >> 4;
    int m0 = wid * 16;
    short8 af[2];
#pragma unroll
    for (int kc = 0; kc < 2; kc++)
        af[kc] = *(const short8*)&As[(m0 + l15) * K1PAD + kc * 32 + q * 8];
    f32x4 acc[8];
#pragma unroll
    for (int nt = 0; nt < 8; nt++) {
        acc[nt] = (f32x4){0.f, 0.f, 0.f, 0.f};
#pragma unroll
        for (int kc = 0; kc < 2; kc++) {
            short8 bf = *(const short8*)&Wt[(nt * 16 + l15) * K1PAD + kc * 32 + q * 8];
            acc[nt] = __builtin_amdgcn_mfma_f32_16x16x32_bf16(af[kc], bf, acc[nt], 0, 0, 0);
        }
    }
#pragma unroll
    for (int nt = 0; nt < 8; nt++) {
        int col = nt * 16 + l15;
        float bv = bsf[col];
#pragma unroll
        for (int r = 0; r < 4; r++) {
            int gr = base + m0 + q * 4 + r;
            if (gr < N) h1[(size_t)gr * HDIM + col] = __float2bfloat16(fmaxf(acc[nt][r] + bv, 0.f));
        }
    }
}

// ---------------- MFMA GEMM B: h2 = relu(Z @ W2 + b2) ----------------
#define K2PAD 136
__global__ __launch_bounds__(256) void k_gemmB(const bf16* __restrict__ Z,
                                               const bf16* __restrict__ W2t,
                                               const bf16* __restrict__ bias,
                                               bf16* __restrict__ outp, int N) {
    __shared__ bf16 As[64 * K2PAD];
    __shared__ bf16 Wt[HDIM * K2PAD];
    __shared__ float bsf[HDIM];
    int tid = threadIdx.x;
    int base = blockIdx.x * 64;
    {
        const uint4* wsrc = (const uint4*)W2t;
        for (int i = tid; i < HDIM * 16; i += 256) {
            int n = i >> 4, c = i & 15;
            *(uint4*)&Wt[n * K2PAD + c * 8] = wsrc[n * 16 + c];
        }
    }
    const uint4* xb = (const uint4*)Z;
    for (int i = tid; i < 64 * 16; i += 256) {
        int r = i >> 4, c = i & 15;
        int gr = base + r; if (gr >= N) gr = N - 1;
        *(uint4*)&As[r * K2PAD + c * 8] = xb[(size_t)gr * 16 + c];
    }
    if (tid < HDIM) bsf[tid] = b2f(bias[tid]);
    __syncthreads();
    int wid = tid >> 6, lane = tid & 63;
    int l15 = lane & 15, q = lane >> 4;
    int m0 = wid * 16;
    short8 af[4];
#pragma unroll
    for (int kc = 0; kc < 4; kc++)
        af[kc] = *(const short8*)&As[(m0 + l15) * K2PAD + kc * 32 + q * 8];
    f32x4 acc[8];
#pragma unroll
    for (int nt = 0; nt < 8; nt++) {
        acc[nt] = (f32x4){0.f, 0.f, 0.f, 0.f};
#pragma unroll
        for (int kc = 0; kc < 4; kc++) {
            short8 bf = *(const short8*)&Wt[(nt * 16 + l15) * K2PAD + kc * 32 + q * 8];
            acc[nt] = __builtin_amdgcn_mfma_f32_16x16x32_bf16(af[kc], bf, acc[nt], 0, 0, 0);
        }
    }
#pragma unroll
    for (int nt = 0; nt < 8; nt++) {
        int col = nt * 16 + l15;
        float bv = bsf[col];
#pragma unroll
        for (int r = 0; r < 4; r++) {
            int gr = base + m0 + q * 4 + r;
            if (gr < N) outp[(size_t)gr * HDIM + col] = __float2bfloat16(fmaxf(acc[nt][r] + bv, 0.f));
        }
    }
}

// ---------------- pool phase A ----------------
__global__ __launch_bounds__(256) void k_pool_sum(const bf16* __restrict__ hact,
                                                  const int* __restrict__ batch,
                                                  float* __restrict__ Gsum,
                                                  float* __restrict__ Gcnt,
                                                  int N, const int* __restrict__ flags) {
    int wave = threadIdx.x >> 6, lane = threadIdx.x & 63;
    int base = blockIdx.x * PROWS;
    int is64 = flags[2];
    const unsigned int* hrow = (const unsigned int*)hact;
    float a0 = 0.f, a1 = 0.f;
    int c = 0, gcur = -1;
    for (int k = 0; k < PROWS / 4; k++) {
        int r = base + wave + 4 * k;
        if (r >= N) break;
        int g = is64 ? batch[2 * r] : batch[r];
        if (g != gcur) {
            if (gcur >= 0) {
                atomicAdd(&Gsum[gcur * HDIM + 2 * lane], a0);
                atomicAdd(&Gsum[gcur * HDIM + 2 * lane + 1], a1);
                if (lane == 0) atomicAdd(&Gcnt[gcur], (float)c);
            }
            a0 = a1 = 0.f; c = 0; gcur = g;
        }
        unsigned int v = hrow[(size_t)r * 64 + lane];
        a0 += bits2f(v & 0xFFFFu);
        a1 += bits2f(v >> 16);
        c++;
    }
    if (gcur >= 0) {
        atomicAdd(&Gsum[gcur * HDIM + 2 * lane], a0);
        atomicAdd(&Gsum[gcur * HDIM + 2 * lane + 1], a1);
        if (lane == 0) atomicAdd(&Gcnt[gcur], (float)c);
    }
}

// ---------------- pool phase B ----------------
__global__ __launch_bounds__(256) void k_pool_fc(const float* __restrict__ Gsum,
                                                 const float* __restrict__ Gcnt,
                                                 const bf16* __restrict__ Wfc,
                                                 const bf16* __restrict__ bfc,
                                                 void* __restrict__ out, int G,
                                                 const int* __restrict__ flags) {
    int wave = threadIdx.x >> 6, lane = threadIdx.x & 63;
    int g = blockIdx.x * 4 + wave;
    if (g >= G) return;
    float inv = 1.0f / fmaxf(Gcnt[g], 1.0f);
    float m0 = Gsum[g * HDIM + 2 * lane] * inv;
    float m1 = Gsum[g * HDIM + 2 * lane + 1] * inv;
    float l0 = m0 * b2f(Wfc[(2 * lane) * 2 + 0]) + m1 * b2f(Wfc[(2 * lane + 1) * 2 + 0]);
    float l1 = m0 * b2f(Wfc[(2 * lane) * 2 + 1]) + m1 * b2f(Wfc[(2 * lane + 1) * 2 + 1]);
    for (int s = 32; s; s >>= 1) { l0 += __shfl_down(l0, s); l1 += __shfl_down(l1, s); }
    if (lane == 0) {
        float z0 = l0 + b2f(bfc[0]);
        float z1 = l1 + b2f(bfc[1]);
        float mx = fmaxf(z0, z1);
        float e0 = expf(z0 - mx), e1 = expf(z1 - mx);
        float s = e0 + e1;
        float p0 = e0 / s, p1 = e1 / s;
        if (flags[0]) {
            ((float*)out)[2 * g + 0] = p0;
            ((float*)out)[2 * g + 1] = p1;
        } else {
            ((bf16*)out)[2 * g + 0] = __float2bfloat16(p0);
            ((bf16*)out)[2 * g + 1] = __float2bfloat16(p1);
        }
    }
}

extern "C" void kernel_launch(void* const* d_in, const int* in_sizes, int n_in,
                              void* d_out, int out_size, void* d_ws, size_t ws_size,
                              hipStream_t stream) {
    const void* x    = d_in[0];
    const int*  edge = (const int*)d_in[1];
    const int*  batch= (const int*)d_in[2];
    const void* W1  = d_in[4];
    const void* b1  = d_in[5];
    const void* W2  = d_in[6];
    const void* b2  = d_in[7];
    const void* Wfc = d_in[8];
    const void* bfc = d_in[9];

    int N = in_sizes[0] / FDIM;   // 100000
    int E = in_sizes[1] / 2;      // 1000000
    int G = out_size / 2;         // 512
    int NP = (N + SCHUNK - 1) / SCHUNK;
    int Eh = (E + 1) / 2;

    int*   flags  = (int*)d_ws;
    float* dinv   = (float*)((char*)d_ws + 64);
    int*   count  = (int*)(dinv + N);                    // memset group start
    float* Gsum   = (float*)(count + N);
    float* Gcnt   = Gsum + (size_t)G * HDIM;             // memset group end
    int*   rowptr = (int*)(Gcnt + G);
    int*   parts  = rowptr + N;
    int*   partsx = parts + 256;
    int*   rank   = partsx + 256;
    int*   srclist= rank + E;
    bf16*  Abuf   = (bf16*)(srclist + E);
    bf16*  Bbuf   = Abuf + (size_t)N * HDIM;
    bf16*  b1c    = Bbuf + (size_t)N * HDIM;
    bf16*  b2c    = b1c + HDIM;
    bf16*  Wfcc   = b2c + HDIM;
    bf16*  bfcc   = Wfcc + 256;
    bf16*  W1t    = bfcc + 64;
    bf16*  W2t    = W1t + FDIM * HDIM;

    bf16* Xb = Abuf;                       // N*64
    bf16* Y  = Abuf + (size_t)N * FDIM;    // N*64
    bf16* Z  = Abuf;                       // N*128

    k_prep_flags<<<1, 192, 0, stream>>>((const unsigned short*)W1, edge, batch, flags);
    k_prep_conv<<<32, 256, 0, stream>>>(W1, b1, W2, b2, Wfc, bfc, flags,
                                        W1t, W2t, b1c, b2c, Wfcc, bfcc);
    k_convX<<<(N * 16 + 255) / 256, 256, 0, stream>>>(x, Xb, N * 16, flags);

    hipMemsetAsync(count, 0, ((size_t)N + (size_t)G * HDIM + G) * sizeof(int), stream);
    k_count<<<(Eh + 255) / 256, 256, 0, stream>>>(edge, count, rank, E, Eh, flags);
    k_scan_partial<<<NP, 256, 0, stream>>>(count, parts, N);
    k_scan_parts<<<1, 256, 0, stream>>>(parts, partsx, NP);
    k_scan_final<<<NP, 512, 0, stream>>>(count, partsx, rowptr, dinv, N);
    k_fill<<<(Eh + 255) / 256, 256, 0, stream>>>(edge, rowptr, rank, srclist, E, Eh, flags);

    // layer 1
    k_agg64<<<(N + 3) / 4, 256, 0, stream>>>(Xb, srclist, rowptr, count, dinv, Y, N);
    k_gemmA<<<(N + 63) / 64, 256, 0, stream>>>(Y, W1t, b1c, Bbuf, N);

    // layer 2
    k_agg128<<<(N + 3) / 4, 256, 0, stream>>>(Bbuf, srclist, rowptr, count, dinv, Z, N);
    k_gemmB<<<(N + 63) / 64, 256, 0, stream>>>(Z, W2t, b2c, Bbuf, N);

    // pool + fc + softmax
    k_pool_sum<<<(N + PROWS - 1) / PROWS, 256, 0, stream>>>(Bbuf, batch, Gsum, Gcnt, N, flags);
    k_pool_fc<<<(G + 3) / 4, 256, 0, stream>>>(Gsum, Gcnt, Wfcc, bfcc, d_out, G, flags);
}